// Round 14
// baseline (879.924 us; speedup 1.0000x reference)
//
#include <hip/hip_runtime.h>
#include <hip/hip_bf16.h>
#include <stdint.h>

#define DIMQ   1024
#define NHEADS 16
#define HD     64
#define NEXP   8
#define DFF    4096
#define NTOK   8192
#define TSEQ   1024
#define BATCH  8
#define MAXTILES 72   // sum ceil(Me/256) <= 16384/256 + 8

typedef unsigned short u16;
typedef unsigned int   u32;
typedef __attribute__((ext_vector_type(8))) short bf16x8;
typedef __attribute__((ext_vector_type(4))) float f32x4;

__device__ __forceinline__ float bf_lo(u32 w) { return __uint_as_float(w << 16); }
__device__ __forceinline__ float bf_hi(u32 w) { return __uint_as_float(w & 0xffff0000u); }
__device__ __forceinline__ u16 f2bf(float f) {
  u32 x = __float_as_uint(f);
  return (u16)((x + 0x7fffu + ((x >> 16) & 1u)) >> 16);
}

// async 16B global -> LDS (linear dest: wave base + lane*16)
__device__ __forceinline__ void gload16(const u16* g, u16* l) {
  __builtin_amdgcn_global_load_lds((const __attribute__((address_space(1))) u32*)g,
                                   (__attribute__((address_space(3))) u32*)l, 16, 0, 0);
}

// ---------------- convert f32 -> bf16 ----------------
__global__ __launch_bounds__(256) void cvt_f32_bf16(const float* __restrict__ in,
                                                    u16* __restrict__ out, int n) {
  int i = (blockIdx.x * 256 + threadIdx.x) * 4;
  if (i >= n) return;
  float4 v = *(const float4*)(in + i);
  ushort4 o;
  o.x = f2bf(v.x); o.y = f2bf(v.y); o.z = f2bf(v.z); o.w = f2bf(v.w);
  *(ushort4*)(out + i) = o;
}

// ---------------- batched transpose f32[R][C] -> bf16[C][R] ----------------
__global__ __launch_bounds__(256) void transpose_f32_bf16(
    const float* __restrict__ in, u16* __restrict__ out, int R, int C) {
  __shared__ float tile[32][33];
  size_t base = (size_t)blockIdx.z * (size_t)R * (size_t)C;
  int tx = threadIdx.x & 31, ty = threadIdx.x >> 5;
  int c = blockIdx.x * 32 + tx;
#pragma unroll
  for (int i = 0; i < 4; i++) {
    int r = blockIdx.y * 32 + ty + i * 8;
    tile[ty + i * 8][tx] = in[base + (size_t)r * C + c];
  }
  __syncthreads();
  int rr = blockIdx.y * 32 + tx;
#pragma unroll
  for (int i = 0; i < 4; i++) {
    int cc = blockIdx.x * 32 + ty + i * 8;
    out[base + (size_t)cc * R + rr] = f2bf(tile[tx][ty + i * 8]);
  }
}

// ---------------- 128x128 MFMA GEMM core, BK=32, dbuf, R4-ordering ----------------
template <bool GATHER, bool RELU, bool TRANSC>
__device__ __forceinline__ void gemm_core(
    const u16* __restrict__ A, const u16* __restrict__ Bt,
    const float* __restrict__ bias, u16* __restrict__ C,
    int M, int N, int K, const int* __restrict__ gidx,
    int rowbase, int colbase) {
  __shared__ u16 As[2][128 * 32];
  __shared__ u16 Bs[2][128 * 32];
  const int tid = threadIdx.x;
  const int lane = tid & 63;
  const int wave = tid >> 6;
  const int wr = wave >> 1, wc = wave & 1;
  const int lr = lane & 15, kg = lane >> 4;

  f32x4 acc[4][4];
#pragma unroll
  for (int m = 0; m < 4; m++)
#pragma unroll
    for (int n = 0; n < 4; n++) acc[m][n] = (f32x4){0.f, 0.f, 0.f, 0.f};

  const int r0 = tid >> 2, seg = tid & 3;
  const int slog = seg ^ ((r0 >> 1) & 3);
  int ar0 = rowbase + r0;      if (ar0 >= M) ar0 = M - 1;
  int ar1 = rowbase + r0 + 64; if (ar1 >= M) ar1 = M - 1;
  const long arow0 = GATHER ? gidx[ar0] : ar0;
  const long arow1 = GATHER ? gidx[ar1] : ar1;
  const u16* Aptr0 = A + (size_t)arow0 * K + slog * 8;
  const u16* Aptr1 = A + (size_t)arow1 * K + slog * 8;
  const u16* Bptr0 = Bt + (size_t)(colbase + r0) * K + slog * 8;
  const u16* Bptr1 = Bt + (size_t)(colbase + r0 + 64) * K + slog * 8;

  const int swz = (lr >> 1) & 3;

#define STAGE128(buf, k0)                                   \
  {                                                         \
    gload16(Aptr0 + (k0), &As[buf][tid * 8]);               \
    gload16(Aptr1 + (k0), &As[buf][2048 + tid * 8]);        \
    gload16(Bptr0 + (k0), &Bs[buf][tid * 8]);               \
    gload16(Bptr1 + (k0), &Bs[buf][2048 + tid * 8]);        \
  }

  const int NT = K >> 5;
  STAGE128(0, 0);
  __syncthreads();   // prologue drain (once)
  for (int t = 0; t < NT; t++) {
    const int buf = t & 1;
    if (t + 1 < NT) STAGE128(buf ^ 1, (t + 1) << 5);
    bf16x8 af[4], bfr[4];
#pragma unroll
    for (int m = 0; m < 4; m++)
      af[m] = *(const bf16x8*)(&As[buf][(wr * 64 + m * 16 + lr) * 32 + ((kg ^ swz) * 8)]);
#pragma unroll
    for (int n = 0; n < 4; n++)
      bfr[n] = *(const bf16x8*)(&Bs[buf][(wc * 64 + n * 16 + lr) * 32 + ((kg ^ swz) * 8)]);
#pragma unroll
    for (int m = 0; m < 4; m++)
#pragma unroll
      for (int n = 0; n < 4; n++)
        acc[m][n] = __builtin_amdgcn_mfma_f32_16x16x32_bf16(af[m], bfr[n], acc[m][n], 0, 0, 0);
    __syncthreads();   // drains STAGE(t+1) issued a compute-phase ago; frees buf
  }
#undef STAGE128

#pragma unroll
  for (int n = 0; n < 4; n++) {
    int col = colbase + wc * 64 + n * 16 + lr;
    float bv = bias[col];
#pragma unroll
    for (int m = 0; m < 4; m++) {
      int row0 = rowbase + wr * 64 + m * 16 + kg * 4;
      if (TRANSC) {
        if (row0 + 3 < M) {
          ushort4 pk;
          pk.x = f2bf(acc[m][n][0] + bv);
          pk.y = f2bf(acc[m][n][1] + bv);
          pk.z = f2bf(acc[m][n][2] + bv);
          pk.w = f2bf(acc[m][n][3] + bv);
          *(ushort4*)(&C[(size_t)col * M + row0]) = pk;
        } else {
#pragma unroll
          for (int r = 0; r < 4; r++)
            if (row0 + r < M) C[(size_t)col * M + row0 + r] = f2bf(acc[m][n][r] + bv);
        }
      } else {
#pragma unroll
        for (int r = 0; r < 4; r++) {
          int row = row0 + r;
          if (row < M) {
            float v = acc[m][n][r] + bv;
            if (RELU) v = fmaxf(v, 0.f);
            C[(size_t)row * N + col] = f2bf(v);
          }
        }
      }
    }
  }
}

__global__ __launch_bounds__(256) void gemm_bt_kernel(
    const u16* __restrict__ A, const u16* __restrict__ Bt,
    const float* __restrict__ bias, u16* __restrict__ C, int M, int N, int K) {
  gemm_core<false, false, false>(A, Bt, bias, C, M, N, K, nullptr,
                                 blockIdx.y * 128, blockIdx.x * 128);
}

__global__ __launch_bounds__(256) void gemm_bt_tc_kernel(
    const u16* __restrict__ A, const u16* __restrict__ Bt,
    const float* __restrict__ bias, u16* __restrict__ C, int M, int N, int K) {
  gemm_core<false, false, true>(A, Bt, bias, C, M, N, K, nullptr,
                                blockIdx.y * 128, blockIdx.x * 128);
}

// ---------------- 256x256 8-phase MFMA GEMM core (MoE) ----------------
// BM=BN=256, BK=64, 512 threads = 8 waves (2Mx4N), per-wave 128x64, dbuf 128KB.
// Per K-tile: 8 phases of {prefetch 2 gloads (p<4) | ds_read phase fragments ->
// raw s_barrier -> lgkmcnt(0)+sched_barrier -> setprio(1) -> 8 MFMA -> setprio(0)
// -> raw s_barrier}. Tile boundary: vmcnt(0) (loads >=4 phases old, ~free) + barrier.
// Raw barriers carry prefetch across phases; waves de-lockstep so one wave's
// ds_read overlaps another's MFMA (T3 structure; T5 setprio now has role-split).
template <bool GATHER, bool RELU>
__device__ __forceinline__ void gemm256_core(
    const u16* __restrict__ A, const u16* __restrict__ Bt,
    const float* __restrict__ bias, u16* __restrict__ C,
    int M, int N, int K, const int* __restrict__ gidx,
    int rowbase, int colbase) {
  __shared__ u16 lds[2][2][256 * 64];   // [buf][0=A,1=B][row*64 + k] : 128 KiB
  const int tid = threadIdx.x;
  const int lane = tid & 63;
  const int wave = tid >> 6;            // 0..7
  const int wr = wave >> 2;             // 0..1  M-half
  const int wcol = wave & 3;            // 0..3  N-quarter
  const int lr = lane & 15, kg = lane >> 4;

  f32x4 acc[8][4];
#pragma unroll
  for (int m = 0; m < 8; m++)
#pragma unroll
    for (int n = 0; n < 4; n++) acc[m][n] = (f32x4){0.f, 0.f, 0.f, 0.f};

  const int srow0 = tid >> 3, sphys = tid & 7;
  const u16* asrc[4];
  const u16* bsrc[4];
#pragma unroll
  for (int j = 0; j < 4; j++) {
    int row = srow0 + j * 64;
    int ls = sphys ^ (row & 7);
    int ar = rowbase + row; if (ar >= M) ar = M - 1;
    long ga = GATHER ? gidx[ar] : ar;
    asrc[j] = A + (size_t)ga * K + ls * 8;
    bsrc[j] = Bt + (size_t)(colbase + row) * K + ls * 8;
  }

  // prologue: stage tile 0 fully, drain once
#pragma unroll
  for (int j = 0; j < 4; j++) {
    gload16(asrc[j], &lds[0][0][tid * 8 + j * 4096]);
    gload16(bsrc[j], &lds[0][1][tid * 8 + j * 4096]);
  }
  __syncthreads();

  const int NT = K >> 6;
  for (int t = 0; t < NT; t++) {
    const int cur = t & 1;
    const bool pf = (t + 1 < NT);
    const int k1 = (t + 1) << 6;
    bf16x8 bfr[4][2];
#pragma unroll
    for (int p = 0; p < 8; p++) {
      // prefetch next tile: 2 loads per phase, phases 0..3 (last issue 4 phases before use)
      if (p < 4 && pf) {
        gload16(asrc[p] + k1, &lds[cur ^ 1][0][tid * 8 + p * 4096]);
        gload16(bsrc[p] + k1, &lds[cur ^ 1][1][tid * 8 + p * 4096]);
      }
      // ds_read this phase's fragments (B fragments once, at phase 0)
      if (p == 0) {
#pragma unroll
        for (int nr = 0; nr < 4; nr++) {
          int rb = wcol * 64 + nr * 16 + lr;
#pragma unroll
          for (int kk = 0; kk < 2; kk++)
            bfr[nr][kk] = *(const bf16x8*)(&lds[cur][1][rb * 64 + (((kk * 4 + kg) ^ (rb & 7)) * 8)]);
        }
      }
      int ra = wr * 128 + p * 16 + lr;
      bf16x8 a0 = *(const bf16x8*)(&lds[cur][0][ra * 64 + ((kg ^ (ra & 7)) * 8)]);
      bf16x8 a1 = *(const bf16x8*)(&lds[cur][0][ra * 64 + (((4 + kg) ^ (ra & 7)) * 8)]);
      __builtin_amdgcn_s_barrier();                       // raw: no vmcnt drain
      asm volatile("s_waitcnt lgkmcnt(0)" ::: "memory");  // phase ds_reads done
      __builtin_amdgcn_sched_barrier(0);                  // rule #18: pin MFMA after wait
      __builtin_amdgcn_s_setprio(1);
#pragma unroll
      for (int nr = 0; nr < 4; nr++) {
        acc[p][nr] = __builtin_amdgcn_mfma_f32_16x16x32_bf16(a0, bfr[nr][0], acc[p][nr], 0, 0, 0);
        acc[p][nr] = __builtin_amdgcn_mfma_f32_16x16x32_bf16(a1, bfr[nr][1], acc[p][nr], 0, 0, 0);
      }
      __builtin_amdgcn_s_setprio(0);
      __builtin_amdgcn_s_barrier();                       // raw
    }
    // tile boundary: next tile's loads (issued phases 0..3, >=4 phases old) must land
    if (pf) asm volatile("s_waitcnt vmcnt(0)" ::: "memory");
    __builtin_amdgcn_s_barrier();   // all waves waited -> lds[cur^1] complete; cur free
  }

  // epilogue: C/D layout col=lane&15, row=(lane>>4)*4+reg
#pragma unroll
  for (int nr = 0; nr < 4; nr++) {
    int col = colbase + wcol * 64 + nr * 16 + lr;
    float bv = bias[col];
#pragma unroll
    for (int mr = 0; mr < 8; mr++) {
      int row0 = rowbase + wr * 128 + mr * 16 + kg * 4;
#pragma unroll
      for (int r = 0; r < 4; r++) {
        int row = row0 + r;
        if (row < M) {
          float v = acc[mr][nr][r] + bv;
          if (RELU) v = fmaxf(v, 0.f);
          C[(size_t)row * N + col] = f2bf(v);
        }
      }
    }
  }
}

// flat tile grid: blockIdx.y = global row-tile; tilestart[e] = prefix of ceil(cnt[e]/256).
__device__ __forceinline__ bool tile_lookup(const int* __restrict__ tilestart,
                                            int t, int& e, int& rowtile) {
  int total = tilestart[8];
  if (t >= total) return false;
  e = 0;
#pragma unroll
  for (int i = 1; i < 8; i++) if (t >= tilestart[i]) e = i;
  rowtile = t - tilestart[e];
  return true;
}

__global__ __launch_bounds__(512, 2) void moe_gemm1_kernel(
    const u16* __restrict__ x1b, const u16* __restrict__ W1t,
    const float* __restrict__ B1, u16* __restrict__ he,
    const int* __restrict__ cnt, const int* __restrict__ off,
    const int* __restrict__ tilestart, const int* __restrict__ idxlist) {
  int e, rowtile;
  if (!tile_lookup(tilestart, blockIdx.y, e, rowtile)) return;
  int M = cnt[e];
  gemm256_core<true, true>(x1b, W1t + (size_t)e * DFF * DIMQ, B1 + e * DFF,
                           he + (size_t)off[e] * DFF, M, DFF, DIMQ, idxlist + off[e],
                           rowtile * 256, blockIdx.x * 256);
}

__global__ __launch_bounds__(512, 2) void moe_gemm2_kernel(
    const u16* __restrict__ he, const u16* __restrict__ W2t,
    const float* __restrict__ B2, u16* __restrict__ yslot,
    const int* __restrict__ cnt, const int* __restrict__ off,
    const int* __restrict__ tilestart) {
  int e, rowtile;
  if (!tile_lookup(tilestart, blockIdx.y, e, rowtile)) return;
  int M = cnt[e];
  gemm256_core<false, false>(he + (size_t)off[e] * DFF, W2t + (size_t)e * DIMQ * DFF,
                             B2 + e * DIMQ, yslot + (size_t)off[e] * DIMQ, M, DIMQ, DFF, nullptr,
                             rowtile * 256, blockIdx.x * 256);
}

// ---------------- MFMA flash attention, KVBLK=64 ----------------
__global__ __launch_bounds__(256) void attn_mfma_kernel(
    const u16* __restrict__ qb, const u16* __restrict__ kb,
    const u16* __restrict__ vbT, const int* __restrict__ amask,
    u16* __restrict__ hb) {
  __shared__ u16 Ks[64 * 64];
  __shared__ u16 VTs[64 * 64];
  __shared__ u16 Ps[4][16 * 64];
  __shared__ float mbias[64];

  const int b = blockIdx.y >> 4;
  const int h = blockIdx.y & 15;
  const int qb0 = blockIdx.x * 64;
  const int tid = threadIdx.x;
  const int lane = tid & 63;
  const int wq = tid >> 6;
  const int r16 = lane & 15;
  const int kg = lane >> 4;
  const int qrow0 = qb0 + wq * 16;

  bf16x8 qf[2];
  {
    const u16* qp = qb + ((size_t)(b * TSEQ + qrow0 + r16)) * DIMQ + h * HD + kg * 8;
    qf[0] = *(const bf16x8*)(qp);
    qf[1] = *(const bf16x8*)(qp + 32);
  }
  f32x4 acc[4];
#pragma unroll
  for (int db = 0; db < 4; db++) acc[db] = (f32x4){0.f, 0.f, 0.f, 0.f};
  float m_run[4], l_run[4];
#pragma unroll
  for (int i = 0; i < 4; i++) { m_run[i] = -3.0e38f; l_run[i] = 0.f; }

  const int kr0 = tid >> 3, ks0 = tid & 7;
  const int kr1 = (tid + 256) >> 3, ks1 = tid & 7;
  const u16* kgb = kb + (size_t)(b * TSEQ) * DIMQ + h * HD;
  const u16* vgb = vbT + (size_t)(h * HD) * NTOK + (size_t)b * TSEQ;

  const int nt = (qb0 + 64) >> 6;
  for (int kt = 0; kt < nt; kt++) {
    const int k0g = kt * 64;
    __syncthreads();
    {
      uint4 kv0 = *(const uint4*)(kgb + (size_t)(k0g + kr0) * DIMQ + ks0 * 8);
      *(uint4*)(&Ks[kr0 * 64 + ((ks0 ^ (kr0 & 7)) * 8)]) = kv0;
      uint4 kv1 = *(const uint4*)(kgb + (size_t)(k0g + kr1) * DIMQ + ks1 * 8);
      *(uint4*)(&Ks[kr1 * 64 + ((ks1 ^ (kr1 & 7)) * 8)]) = kv1;
      uint4 vv0 = *(const uint4*)(vgb + (size_t)kr0 * NTOK + k0g + ks0 * 8);
      *(uint4*)(&VTs[kr0 * 64 + ((ks0 ^ (kr0 & 7)) * 8)]) = vv0;
      uint4 vv1 = *(const uint4*)(vgb + (size_t)kr1 * NTOK + k0g + ks1 * 8);
      *(uint4*)(&VTs[kr1 * 64 + ((ks1 ^ (kr1 & 7)) * 8)]) = vv1;
      if (tid < 64) mbias[tid] = amask[b * TSEQ + k0g + tid] ? 0.f : -1e9f;
    }
    __syncthreads();
    if (k0g < qrow0 + 16) {
      f32x4 s[4];
#pragma unroll
      for (int g = 0; g < 4; g++) s[g] = (f32x4){0.f, 0.f, 0.f, 0.f};
#pragma unroll
      for (int g = 0; g < 4; g++) {
        int key = g * 16 + r16;
        bf16x8 ka  = *(const bf16x8*)(&Ks[key * 64 + ((kg ^ (key & 7)) * 8)]);
        bf16x8 kb2 = *(const bf16x8*)(&Ks[key * 64 + (((4 + kg) ^ (key & 7)) * 8)]);
        s[g] = __builtin_amdgcn_mfma_f32_16x16x32_bf16(qf[0], ka, s[g], 0, 0, 0);
        s[g] = __builtin_amdgcn_mfma_f32_16x16x32_bf16(qf[1], kb2, s[g], 0, 0, 0);
      }
      float mb[4] = {mbias[r16], mbias[16 + r16], mbias[32 + r16], mbias[48 + r16]};
      float sv[4][4], tm[4];
#pragma unroll
      for (int i = 0; i < 4; i++) {
        int qg = qrow0 + kg * 4 + i;
        tm[i] = -3.0e38f;
#pragma unroll
        for (int g = 0; g < 4; g++) {
          float a = s[g][i] * 0.125f + mb[g];
          if (k0g + g * 16 + r16 > qg) a = -3.0e38f;
          sv[g][i] = a;
          tm[i] = fmaxf(tm[i], a);
        }
      }
#pragma unroll
      for (int mk = 1; mk < 16; mk <<= 1) {
#pragma unroll
        for (int i = 0; i < 4; i++) tm[i] = fmaxf(tm[i], __shfl_xor(tm[i], mk));
      }
#pragma unroll
      for (int i = 0; i < 4; i++) {
        float nm = fmaxf(m_run[i], tm[i]);
        float sc = __expf(m_run[i] - nm);
        m_run[i] = nm;
        int qrl = kg * 4 + i;
        float lsum = 0.f;
#pragma unroll
        for (int g = 0; g < 4; g++) {
          float p = __expf(sv[g][i] - nm);
          lsum += p;
          int slotL = g * 2 + (r16 >> 3);
          Ps[wq][qrl * 64 + ((slotL ^ (qrl & 7)) * 8) + (r16 & 7)] = f2bf(p);
        }
        l_run[i] = l_run[i] * sc + lsum;
#pragma unroll
        for (int db = 0; db < 4; db++) acc[db][i] *= sc;
      }
      bf16x8 pf0 = *(const bf16x8*)(&Ps[wq][r16 * 64 + ((kg ^ (r16 & 7)) * 8)]);
      bf16x8 pf1 = *(const bf16x8*)(&Ps[wq][r16 * 64 + (((4 + kg) ^ (r16 & 7)) * 8)]);
#pragma unroll
      for (int db = 0; db < 4; db++) {
        int d = db * 16 + r16;
        bf16x8 vf0 = *(const bf16x8*)(&VTs[d * 64 + ((kg ^ (d & 7)) * 8)]);
        bf16x8 vf1 = *(const bf16x8*)(&VTs[d * 64 + (((4 + kg) ^ (d & 7)) * 8)]);
        acc[db] = __builtin_amdgcn_mfma_f32_16x16x32_bf16(pf0, vf0, acc[db], 0, 0, 0);
        acc[db] = __builtin_amdgcn_mfma_f32_16x16x32_bf16(pf1, vf1, acc[db], 0, 0, 0);
      }
    }
  }
#pragma unroll
  for (int mk = 1; mk < 16; mk <<= 1) {
#pragma unroll
    for (int i = 0; i < 4; i++) l_run[i] += __shfl_xor(l_run[i], mk);
  }
#pragma unroll
  for (int i = 0; i < 4; i++) {
    float inv = 1.f / l_run[i];
    int qg = qrow0 + kg * 4 + i;
    u16* op = hb + ((size_t)(b * TSEQ + qg)) * DIMQ + h * HD + r16;
#pragma unroll
    for (int db = 0; db < 4; db++) op[db * 16] = f2bf(acc[db][i] * inv);
  }
}

// ---------------- add + layernorm (x + h) -> x1 f32 and x1b bf16 ----------------
__global__ __launch_bounds__(256) void addln_kernel(
    const float* __restrict__ xin, const u16* __restrict__ hres,
    const float* __restrict__ g, const float* __restrict__ beta,
    float* __restrict__ x1, u16* __restrict__ x1b) {
  __shared__ float red[8];
  int t = blockIdx.x;
  int d = threadIdx.x * 4;
  size_t base = (size_t)t * DIMQ + d;
  float4 xv = *(const float4*)(xin + base);
  uint2 hu = *(const uint2*)(hres + base);
  float v0 = xv.x + bf_lo(hu.x), v1 = xv.y + bf_hi(hu.x);
  float v2 = xv.z + bf_lo(hu.y), v3 = xv.w + bf_hi(hu.y);
  float s1 = v0 + v1 + v2 + v3;
  float s2 = v0 * v0 + v1 * v1 + v2 * v2 + v3 * v3;
#pragma unroll
  for (int off = 32; off; off >>= 1) {
    s1 += __shfl_down(s1, off);
    s2 += __shfl_down(s2, off);
  }
  int w = threadIdx.x >> 6;
  if ((threadIdx.x & 63) == 0) { red[w] = s1; red[4 + w] = s2; }
  __syncthreads();
  float S1 = red[0] + red[1] + red[2] + red[3];
  float S2 = red[4] + red[5] + red[6] + red[7];
  float m = S1 * (1.f / DIMQ);
  float var = S2 * (1.f / DIMQ) - m * m;
  float rs = rsqrtf(var + 1e-5f);
  float4 gv = *(const float4*)(g + d);
  float4 bv = *(const float4*)(beta + d);
  float o0 = (v0 - m) * rs * gv.x + bv.x;
  float o1 = (v1 - m) * rs * gv.y + bv.y;
  float o2 = (v2 - m) * rs * gv.z + bv.z;
  float o3 = (v3 - m) * rs * gv.w + bv.w;
  *(float4*)(x1 + base) = make_float4(o0, o1, o2, o3);
  uint2 pu;
  pu.x = (u32)f2bf(o0) | ((u32)f2bf(o1) << 16);
  pu.y = (u32)f2bf(o2) | ((u32)f2bf(o3) << 16);
  *(uint2*)(x1b + base) = pu;
}

// ---------------- router: logits, softmax, top-2 (NO global atomics) ----------------
__global__ __launch_bounds__(256) void router_kernel(
    const float* __restrict__ x1, const float* __restrict__ rw,
    const float* __restrict__ rb, int* __restrict__ topi,
    float* __restrict__ gkout, float* __restrict__ probs) {
  int t = blockIdx.x * 4 + (threadIdx.x >> 6);
  int l = threadIdx.x & 63;
  float acc[8];
#pragma unroll
  for (int e = 0; e < 8; e++) acc[e] = 0.f;
  const float* xr = x1 + (size_t)t * DIMQ;
  for (int k = l; k < DIMQ; k += 64) {
    float xv = xr[k];
    const float* w = rw + (size_t)k * 8;
#pragma unroll
    for (int e = 0; e < 8; e++) acc[e] += xv * w[e];
  }
#pragma unroll
  for (int e = 0; e < 8; e++) {
#pragma unroll
    for (int off = 32; off; off >>= 1) acc[e] += __shfl_down(acc[e], off);
  }
  if (l == 0) {
    float lg[8], p[8];
    float mx = -3e38f;
#pragma unroll
    for (int e = 0; e < 8; e++) { lg[e] = acc[e] + rb[e]; mx = fmaxf(mx, lg[e]); }
    float sum = 0.f;
#pragma unroll
    for (int e = 0; e < 8; e++) { p[e] = expf(lg[e] - mx); sum += p[e]; }
    float isum = 1.f / sum;
#pragma unroll
    for (int e = 0; e < 8; e++) p[e] *= isum;
    int e0 = 0;
#pragma unroll
    for (int e = 1; e < 8; e++) if (p[e] > p[e0]) e0 = e;
    int e1 = (e0 == 0) ? 1 : 0;
#pragma unroll
    for (int e = 0; e < 8; e++) if (e != e0 && p[e] > p[e1]) e1 = e;
    float s2 = p[e0] + p[e1];
    topi[2 * t] = e0; topi[2 * t + 1] = e1;
    gkout[2 * t] = p[e0] / s2; gkout[2 * t + 1] = p[e1] / s2;
    float* pp = probs + (size_t)t * 8;
#pragma unroll
    for (int e = 0; e < 8; e++) pp[e] = p[e];
  }
}

// ---------------- stats: cnt[e], Psum[e] with block-aggregated atomics ----------------
__global__ __launch_bounds__(256) void stats_kernel(
    const float* __restrict__ probs, const int* __restrict__ topi,
    int* __restrict__ cnt, float* __restrict__ Psum) {
  __shared__ float sps[4][8];
  __shared__ int   slc[4][8];
  float ps[8];
  int lc[8];
#pragma unroll
  for (int e = 0; e < 8; e++) { ps[e] = 0.f; lc[e] = 0; }
  int t = blockIdx.x * 256 + threadIdx.x;
  {
    const float* p = probs + (size_t)t * 8;
#pragma unroll
    for (int e = 0; e < 8; e++) ps[e] += p[e];
    lc[topi[2 * t]]++;
    lc[topi[2 * t + 1]]++;
  }
#pragma unroll
  for (int e = 0; e < 8; e++) {
#pragma unroll
    for (int off = 32; off; off >>= 1) {
      ps[e] += __shfl_down(ps[e], off);
      lc[e] += __shfl_down(lc[e], off);
    }
  }
  int w = threadIdx.x >> 6;
  if ((threadIdx.x & 63) == 0) {
#pragma unroll
    for (int e = 0; e < 8; e++) { sps[w][e] = ps[e]; slc[w][e] = lc[e]; }
  }
  __syncthreads();
  if (threadIdx.x < 8) {
    float fp = sps[0][threadIdx.x] + sps[1][threadIdx.x] + sps[2][threadIdx.x] + sps[3][threadIdx.x];
    int   fc = slc[0][threadIdx.x] + slc[1][threadIdx.x] + slc[2][threadIdx.x] + slc[3][threadIdx.x];
    atomicAdd(&Psum[threadIdx.x], fp);
    atomicAdd(&cnt[threadIdx.x], fc);
  }
}

__global__ void offsets_kernel(const int* __restrict__ cnt, const float* __restrict__ Psum,
                               int* __restrict__ off, int* __restrict__ fill,
                               int* __restrict__ tilestart, float* __restrict__ lb_out) {
  if (threadIdx.x == 0 && blockIdx.x == 0) {
    int o = 0, ts = 0;
    float lb = 0.f;
    for (int e = 0; e < NEXP; e++) {
      off[e] = o;
      fill[e] = o;
      tilestart[e] = ts;
      ts += (cnt[e] + 255) >> 8;
      o += cnt[e];
      lb += ((float)cnt[e] / (float)NTOK) * (Psum[e] / (float)NTOK);
    }
    tilestart[NEXP] = ts;
    lb_out[0] = (float)NEXP * lb;
  }
}

// ---------------- listbuild: block-aggregated slot assignment ----------------
__global__ __launch_bounds__(256) void listbuild_kernel(
    const int* __restrict__ topi, int* fill, int* __restrict__ idxlist,
    int* __restrict__ posmap) {
  __shared__ int bcnt[8];
  __shared__ int base[8];
  __shared__ int bofs[8];
  int t = blockIdx.x * 256 + threadIdx.x;
  if (threadIdx.x < 8) { bcnt[threadIdx.x] = 0; bofs[threadIdx.x] = 0; }
  __syncthreads();
  int e0 = topi[2 * t], e1 = topi[2 * t + 1];
  atomicAdd(&bcnt[e0], 1);
  atomicAdd(&bcnt[e1], 1);
  __syncthreads();
  if (threadIdx.x < 8) base[threadIdx.x] = atomicAdd(&fill[threadIdx.x], bcnt[threadIdx.x]);
  __syncthreads();
  int s0 = base[e0] + atomicAdd(&bofs[e0], 1);
  idxlist[s0] = t;
  posmap[2 * t] = s0;
  int s1 = base[e1] + atomicAdd(&bofs[e1], 1);
  idxlist[s1] = t;
  posmap[2 * t + 1] = s1;
}

// ---------------- final: out = LN(x1 + g0*yslot[p0] + g1*yslot[p1]) ----------------
__global__ __launch_bounds__(256) void finalln_kernel(
    const float* __restrict__ x1, const u16* __restrict__ yslot,
    const int* __restrict__ posmap, const float* __restrict__ gkv,
    const float* __restrict__ g, const float* __restrict__ beta,
    float* __restrict__ out) {
  __shared__ float red[8];
  int t = blockIdx.x;
  int p0 = posmap[2 * t], p1 = posmap[2 * t + 1];
  float g0 = gkv[2 * t], g1 = gkv[2 * t + 1];
  int d = threadIdx.x * 4;
  size_t base = (size_t)t * DIMQ + d;
  float4 xv = *(const float4*)(x1 + base);
  uint2 y0 = *(const uint2*)(yslot + (size_t)p0 * DIMQ + d);
  uint2 y1 = *(const uint2*)(yslot + (size_t)p1 * DIMQ + d);
  float v0 = xv.x + g0 * bf_lo(y0.x) + g1 * bf_lo(y1.x);
  float v1 = xv.y + g0 * bf_hi(y0.x) + g1 * bf_hi(y1.x);
  float v2 = xv.z + g0 * bf_lo(y0.y) + g1 * bf_lo(y1.y);
  float v3 = xv.w + g0 * bf_hi(y0.y) + g1 * bf_hi(y1.y);
  float s1 = v0 + v1 + v2 + v3;
  float s2 = v0 * v0 + v1 * v1 + v2 * v2 + v3 * v3;
#pragma unroll
  for (int off = 32; off; off >>= 1) {
    s1 += __shfl_down(s1, off);
    s2 += __shfl_down(s2, off);
  }
  int w = threadIdx.x >> 6;
  if ((threadIdx.x & 63) == 0) { red[w] = s1; red[4 + w] = s2; }
  __syncthreads();
  float S1 = red[0] + red[1] + red[2] + red[3];
  float S2 = red[4] + red[5] + red[6] + red[7];
  float m = S1 * (1.f / DIMQ);
  float var = S2 * (1.f / DIMQ) - m * m;
  float rs = rsqrtf(var + 1e-5f);
  float4 gv = *(const float4*)(g + d);
  float4 bv = *(const float4*)(beta + d);
  float4 o;
  o.x = (v0 - m) * rs * gv.x + bv.x;
  o.y = (v1 - m) * rs * gv.y + bv.y;
  o.z = (v2 - m) * rs * gv.z + bv.z;
  o.w = (v3 - m) * rs * gv.w + bv.w;
  *(float4*)(out + base) = o;
}

// ---------------- host launch ----------------
extern "C" void kernel_launch(void* const* d_in, const int* in_sizes, int n_in,
                              void* d_out, int out_size, void* d_ws, size_t ws_size,
                              hipStream_t stream) {
  const float* x     = (const float*)d_in[0];
  const int*   amask = (const int*)d_in[1];
  const float* Wq    = (const float*)d_in[2];
  const float* bq    = (const float*)d_in[3];
  const float* Wk    = (const float*)d_in[4];
  const float* bk    = (const float*)d_in[5];
  const float* Wv    = (const float*)d_in[6];
  const float* bv    = (const float*)d_in[7];
  const float* Wo    = (const float*)d_in[8];
  const float* bo    = (const float*)d_in[9];
  const float* g1    = (const float*)d_in[10];
  const float* beta1 = (const float*)d_in[11];
  const float* rw    = (const float*)d_in[12];
  const float* rb    = (const float*)d_in[13];
  const float* W1    = (const float*)d_in[14];
  const float* B1    = (const float*)d_in[15];
  const float* W2    = (const float*)d_in[16];
  const float* B2    = (const float*)d_in[17];
  const float* g2    = (const float*)d_in[18];
  const float* beta2 = (const float*)d_in[19];
  float* out    = (float*)d_out;
  float* lb_out = out + (size_t)NTOK * DIMQ;

  char* ws = (char*)d_ws;
  size_t off_acc = 0;
  auto alloc = [&](size_t bytes) {
    void* p = ws + off_acc;
    off_acc += (bytes + 255) & ~(size_t)255;
    return p;
  };
  u16* xb    = (u16*)alloc((size_t)NTOK * DIMQ * 2);
  u16* qbuf  = (u16*)alloc((size_t)NTOK * DIMQ * 2);
  u16* kbuf  = (u16*)alloc((size_t)NTOK * DIMQ * 2);
  u16* vbufT = (u16*)alloc((size_t)NTOK * DIMQ * 2);  // transposed: [col][row]
  u16* hb    = (u16*)alloc((size_t)NTOK * DIMQ * 2);
  u16* ho    = (u16*)alloc((size_t)NTOK * DIMQ * 2);
  float* x1  = (float*)alloc((size_t)NTOK * DIMQ * 4);
  u16* x1b   = (u16*)alloc((size_t)NTOK * DIMQ * 2);
  u16* Wqt   = (u16*)alloc((size_t)DIMQ * DIMQ * 2);
  u16* Wkt   = (u16*)alloc((size_t)DIMQ * DIMQ * 2);
  u16* Wvt   = (u16*)alloc((size_t)DIMQ * DIMQ * 2);
  u16* Wot   = (u16*)alloc((size_t)DIMQ * DIMQ * 2);
  u16* W1t   = (u16*)alloc((size_t)NEXP * DFF * DIMQ * 2);
  u16* W2t   = (u16*)alloc((size_t)NEXP * DIMQ * DFF * 2);
  u16* he    = (u16*)alloc((size_t)2 * NTOK * DFF * 2);
  u16* yslot = (u16*)alloc((size_t)2 * NTOK * DIMQ * 2);
  char* stats = (char*)alloc(4096);
  int*   cnt   = (int*)stats;
  float* Psum  = (float*)(stats + 32);
  int*   offp  = (int*)(stats + 64);
  int*   fill  = (int*)(stats + 96);
  int*   tilestart = (int*)(stats + 128);   // 9 ints
  int* topi    = (int*)alloc((size_t)NTOK * 2 * 4);
  float* gkbuf = (float*)alloc((size_t)NTOK * 2 * 4);
  int* posmap  = (int*)alloc((size_t)NTOK * 2 * 4);
  int* idxlist = (int*)alloc((size_t)NTOK * 2 * 4);
  float* probs = (float*)alloc((size_t)NTOK * 8 * 4);

  hipMemsetAsync(stats, 0, 192, stream);

  // converts / transposes
  cvt_f32_bf16<<<NTOK * DIMQ / 1024, 256, 0, stream>>>(x, xb, NTOK * DIMQ);
  transpose_f32_bf16<<<dim3(DIMQ / 32, DIMQ / 32, 1), 256, 0, stream>>>(Wq, Wqt, DIMQ, DIMQ);
  transpose_f32_bf16<<<dim3(DIMQ / 32, DIMQ / 32, 1), 256, 0, stream>>>(Wk, Wkt, DIMQ, DIMQ);
  transpose_f32_bf16<<<dim3(DIMQ / 32, DIMQ / 32, 1), 256, 0, stream>>>(Wv, Wvt, DIMQ, DIMQ);
  transpose_f32_bf16<<<dim3(DIMQ / 32, DIMQ / 32, 1), 256, 0, stream>>>(Wo, Wot, DIMQ, DIMQ);
  transpose_f32_bf16<<<dim3(DFF / 32, DIMQ / 32, NEXP), 256, 0, stream>>>(W1, W1t, DIMQ, DFF);
  transpose_f32_bf16<<<dim3(DIMQ / 32, DFF / 32, NEXP), 256, 0, stream>>>(W2, W2t, DFF, DIMQ);

  // attention path
  dim3 gproj(DIMQ / 128, NTOK / 128);
  gemm_bt_kernel<<<gproj, 256, 0, stream>>>(xb, Wqt, bq, qbuf, NTOK, DIMQ, DIMQ);
  gemm_bt_kernel<<<gproj, 256, 0, stream>>>(xb, Wkt, bk, kbuf, NTOK, DIMQ, DIMQ);
  gemm_bt_tc_kernel<<<gproj, 256, 0, stream>>>(xb, Wvt, bv, vbufT, NTOK, DIMQ, DIMQ);
  attn_mfma_kernel<<<dim3(TSEQ / 64, BATCH * NHEADS), 256, 0, stream>>>(qbuf, kbuf, vbufT, amask, hb);
  gemm_bt_kernel<<<gproj, 256, 0, stream>>>(hb, Wot, bo, ho, NTOK, DIMQ, DIMQ);
  addln_kernel<<<NTOK, 256, 0, stream>>>(x, ho, g1, beta1, x1, x1b);

  // MoE path
  router_kernel<<<NTOK / 4, 256, 0, stream>>>(x1, rw, rb, topi, gkbuf, probs);
  stats_kernel<<<NTOK / 256, 256, 0, stream>>>(probs, topi, cnt, Psum);
  offsets_kernel<<<1, 64, 0, stream>>>(cnt, Psum, offp, fill, tilestart, lb_out);
  listbuild_kernel<<<NTOK / 256, 256, 0, stream>>>(topi, fill, idxlist, posmap);
  moe_gemm1_kernel<<<dim3(DFF / 256, MAXTILES, 1), 512, 0, stream>>>(x1b, W1t, B1, he, cnt, offp, tilestart, idxlist);
  moe_gemm2_kernel<<<dim3(DIMQ / 256, MAXTILES, 1), 512, 0, stream>>>(he, W2t, B2, yslot, cnt, offp, tilestart);
  finalln_kernel<<<NTOK, 256, 0, stream>>>(x1, yslot, posmap, gkbuf, g2, beta2, out);
}

// Round 15
// 860.478 us; speedup vs baseline: 1.0226x; 1.0226x over previous
//
#include <hip/hip_runtime.h>
#include <hip/hip_bf16.h>
#include <stdint.h>

#define DIMQ   1024
#define NHEADS 16
#define HD     64
#define NEXP   8
#define DFF    4096
#define NTOK   8192
#define TSEQ   1024
#define BATCH  8
#define MAXTILES 72   // sum ceil(Me/256) <= 16384/256 + 8

typedef unsigned short u16;
typedef unsigned int   u32;
typedef __attribute__((ext_vector_type(8))) short bf16x8;
typedef __attribute__((ext_vector_type(4))) float f32x4;

__device__ __forceinline__ float bf_lo(u32 w) { return __uint_as_float(w << 16); }
__device__ __forceinline__ float bf_hi(u32 w) { return __uint_as_float(w & 0xffff0000u); }
__device__ __forceinline__ u16 f2bf(float f) {
  u32 x = __float_as_uint(f);
  return (u16)((x + 0x7fffu + ((x >> 16) & 1u)) >> 16);
}

// async 16B global -> LDS (linear dest: wave base + lane*16)
__device__ __forceinline__ void gload16(const u16* g, u16* l) {
  __builtin_amdgcn_global_load_lds((const __attribute__((address_space(1))) u32*)g,
                                   (__attribute__((address_space(3))) u32*)l, 16, 0, 0);
}

// ---------------- convert f32 -> bf16 ----------------
__global__ __launch_bounds__(256) void cvt_f32_bf16(const float* __restrict__ in,
                                                    u16* __restrict__ out, int n) {
  int i = (blockIdx.x * 256 + threadIdx.x) * 4;
  if (i >= n) return;
  float4 v = *(const float4*)(in + i);
  ushort4 o;
  o.x = f2bf(v.x); o.y = f2bf(v.y); o.z = f2bf(v.z); o.w = f2bf(v.w);
  *(ushort4*)(out + i) = o;
}

// ---------------- batched transpose f32[R][C] -> bf16[C][R] ----------------
__global__ __launch_bounds__(256) void transpose_f32_bf16(
    const float* __restrict__ in, u16* __restrict__ out, int R, int C) {
  __shared__ float tile[32][33];
  size_t base = (size_t)blockIdx.z * (size_t)R * (size_t)C;
  int tx = threadIdx.x & 31, ty = threadIdx.x >> 5;
  int c = blockIdx.x * 32 + tx;
#pragma unroll
  for (int i = 0; i < 4; i++) {
    int r = blockIdx.y * 32 + ty + i * 8;
    tile[ty + i * 8][tx] = in[base + (size_t)r * C + c];
  }
  __syncthreads();
  int rr = blockIdx.y * 32 + tx;
#pragma unroll
  for (int i = 0; i < 4; i++) {
    int cc = blockIdx.x * 32 + ty + i * 8;
    out[base + (size_t)cc * R + rr] = f2bf(tile[tx][ty + i * 8]);
  }
}

// ---------------- 128x128 MFMA GEMM core, BK=32, dbuf, R4-ordering ----------------
template <bool GATHER, bool RELU, bool TRANSC>
__device__ __forceinline__ void gemm_core(
    const u16* __restrict__ A, const u16* __restrict__ Bt,
    const float* __restrict__ bias, u16* __restrict__ C,
    int M, int N, int K, const int* __restrict__ gidx,
    int rowbase, int colbase) {
  __shared__ u16 As[2][128 * 32];
  __shared__ u16 Bs[2][128 * 32];
  const int tid = threadIdx.x;
  const int lane = tid & 63;
  const int wave = tid >> 6;
  const int wr = wave >> 1, wc = wave & 1;
  const int lr = lane & 15, kg = lane >> 4;

  f32x4 acc[4][4];
#pragma unroll
  for (int m = 0; m < 4; m++)
#pragma unroll
    for (int n = 0; n < 4; n++) acc[m][n] = (f32x4){0.f, 0.f, 0.f, 0.f};

  const int r0 = tid >> 2, seg = tid & 3;
  const int slog = seg ^ ((r0 >> 1) & 3);
  int ar0 = rowbase + r0;      if (ar0 >= M) ar0 = M - 1;
  int ar1 = rowbase + r0 + 64; if (ar1 >= M) ar1 = M - 1;
  const long arow0 = GATHER ? gidx[ar0] : ar0;
  const long arow1 = GATHER ? gidx[ar1] : ar1;
  const u16* Aptr0 = A + (size_t)arow0 * K + slog * 8;
  const u16* Aptr1 = A + (size_t)arow1 * K + slog * 8;
  const u16* Bptr0 = Bt + (size_t)(colbase + r0) * K + slog * 8;
  const u16* Bptr1 = Bt + (size_t)(colbase + r0 + 64) * K + slog * 8;

  const int swz = (lr >> 1) & 3;

#define STAGE128(buf, k0)                                   \
  {                                                         \
    gload16(Aptr0 + (k0), &As[buf][tid * 8]);               \
    gload16(Aptr1 + (k0), &As[buf][2048 + tid * 8]);        \
    gload16(Bptr0 + (k0), &Bs[buf][tid * 8]);               \
    gload16(Bptr1 + (k0), &Bs[buf][2048 + tid * 8]);        \
  }

  const int NT = K >> 5;
  STAGE128(0, 0);
  __syncthreads();   // prologue drain (once)
  for (int t = 0; t < NT; t++) {
    const int buf = t & 1;
    if (t + 1 < NT) STAGE128(buf ^ 1, (t + 1) << 5);
    bf16x8 af[4], bfr[4];
#pragma unroll
    for (int m = 0; m < 4; m++)
      af[m] = *(const bf16x8*)(&As[buf][(wr * 64 + m * 16 + lr) * 32 + ((kg ^ swz) * 8)]);
#pragma unroll
    for (int n = 0; n < 4; n++)
      bfr[n] = *(const bf16x8*)(&Bs[buf][(wc * 64 + n * 16 + lr) * 32 + ((kg ^ swz) * 8)]);
#pragma unroll
    for (int m = 0; m < 4; m++)
#pragma unroll
      for (int n = 0; n < 4; n++)
        acc[m][n] = __builtin_amdgcn_mfma_f32_16x16x32_bf16(af[m], bfr[n], acc[m][n], 0, 0, 0);
    __syncthreads();   // drains STAGE(t+1) issued a compute-phase ago; frees buf
  }
#undef STAGE128

#pragma unroll
  for (int n = 0; n < 4; n++) {
    int col = colbase + wc * 64 + n * 16 + lr;
    float bv = bias[col];
#pragma unroll
    for (int m = 0; m < 4; m++) {
      int row0 = rowbase + wr * 64 + m * 16 + kg * 4;
      if (TRANSC) {
        if (row0 + 3 < M) {
          ushort4 pk;
          pk.x = f2bf(acc[m][n][0] + bv);
          pk.y = f2bf(acc[m][n][1] + bv);
          pk.z = f2bf(acc[m][n][2] + bv);
          pk.w = f2bf(acc[m][n][3] + bv);
          *(ushort4*)(&C[(size_t)col * M + row0]) = pk;
        } else {
#pragma unroll
          for (int r = 0; r < 4; r++)
            if (row0 + r < M) C[(size_t)col * M + row0 + r] = f2bf(acc[m][n][r] + bv);
        }
      } else {
#pragma unroll
        for (int r = 0; r < 4; r++) {
          int row = row0 + r;
          if (row < M) {
            float v = acc[m][n][r] + bv;
            if (RELU) v = fmaxf(v, 0.f);
            C[(size_t)row * N + col] = f2bf(v);
          }
        }
      }
    }
  }
}

__global__ __launch_bounds__(256) void gemm_bt_kernel(
    const u16* __restrict__ A, const u16* __restrict__ Bt,
    const float* __restrict__ bias, u16* __restrict__ C, int M, int N, int K) {
  gemm_core<false, false, false>(A, Bt, bias, C, M, N, K, nullptr,
                                 blockIdx.y * 128, blockIdx.x * 128);
}

__global__ __launch_bounds__(256) void gemm_bt_tc_kernel(
    const u16* __restrict__ A, const u16* __restrict__ Bt,
    const float* __restrict__ bias, u16* __restrict__ C, int M, int N, int K) {
  gemm_core<false, false, true>(A, Bt, bias, C, M, N, K, nullptr,
                                blockIdx.y * 128, blockIdx.x * 128);
}

// ---------------- 256x256 2-phase MFMA GEMM core (MoE) — R4-exact ----------------
template <bool GATHER, bool RELU>
__device__ __forceinline__ void gemm256_core(
    const u16* __restrict__ A, const u16* __restrict__ Bt,
    const float* __restrict__ bias, u16* __restrict__ C,
    int M, int N, int K, const int* __restrict__ gidx,
    int rowbase, int colbase) {
  __shared__ u16 lds[2][2][256 * 64];   // [buf][0=A,1=B][row*64 + k] : 128 KiB
  const int tid = threadIdx.x;
  const int lane = tid & 63;
  const int wave = tid >> 6;            // 0..7
  const int wr = wave >> 2;             // 0..1  M-half
  const int wcol = wave & 3;            // 0..3  N-quarter
  const int lr = lane & 15, kg = lane >> 4;

  f32x4 acc[8][4];
#pragma unroll
  for (int m = 0; m < 8; m++)
#pragma unroll
    for (int n = 0; n < 4; n++) acc[m][n] = (f32x4){0.f, 0.f, 0.f, 0.f};

  const int srow0 = tid >> 3, sphys = tid & 7;
  const u16* asrc[4];
  const u16* bsrc[4];
#pragma unroll
  for (int j = 0; j < 4; j++) {
    int row = srow0 + j * 64;
    int ls = sphys ^ (row & 7);
    int ar = rowbase + row; if (ar >= M) ar = M - 1;
    long ga = GATHER ? gidx[ar] : ar;
    asrc[j] = A + (size_t)ga * K + ls * 8;
    bsrc[j] = Bt + (size_t)(colbase + row) * K + ls * 8;
  }

#define STAGE256(buf, k0)                                              \
  {                                                                    \
    _Pragma("unroll")                                                  \
    for (int j = 0; j < 4; j++) {                                      \
      gload16(asrc[j] + (k0), &lds[buf][0][tid * 8 + j * 4096]);       \
      gload16(bsrc[j] + (k0), &lds[buf][1][tid * 8 + j * 4096]);       \
    }                                                                  \
  }

  STAGE256(0, 0);
  __syncthreads();
  const int NT = K >> 6;
  for (int t = 0; t < NT; t++) {
    const int buf = t & 1;
    if (t + 1 < NT) STAGE256(buf ^ 1, (t + 1) << 6);
    bf16x8 bfr[4][2];
#pragma unroll
    for (int nr = 0; nr < 4; nr++) {
      int rb = wcol * 64 + nr * 16 + lr;
#pragma unroll
      for (int kk = 0; kk < 2; kk++)
        bfr[nr][kk] = *(const bf16x8*)(&lds[buf][1][rb * 64 + (((kk * 4 + kg) ^ (rb & 7)) * 8)]);
    }
#pragma unroll
    for (int mr = 0; mr < 8; mr++) {
      int ra = wr * 128 + mr * 16 + lr;
      bf16x8 a0 = *(const bf16x8*)(&lds[buf][0][ra * 64 + ((kg ^ (ra & 7)) * 8)]);
      bf16x8 a1 = *(const bf16x8*)(&lds[buf][0][ra * 64 + (((4 + kg) ^ (ra & 7)) * 8)]);
#pragma unroll
      for (int nr = 0; nr < 4; nr++) {
        acc[mr][nr] = __builtin_amdgcn_mfma_f32_16x16x32_bf16(a0, bfr[nr][0], acc[mr][nr], 0, 0, 0);
        acc[mr][nr] = __builtin_amdgcn_mfma_f32_16x16x32_bf16(a1, bfr[nr][1], acc[mr][nr], 0, 0, 0);
      }
    }
    __syncthreads();   // drains STAGE(t+1) issued before the 64-MFMA phase
  }
#undef STAGE256

  // epilogue: C/D layout col=lane&15, row=(lane>>4)*4+reg
#pragma unroll
  for (int nr = 0; nr < 4; nr++) {
    int col = colbase + wcol * 64 + nr * 16 + lr;
    float bv = bias[col];
#pragma unroll
    for (int mr = 0; mr < 8; mr++) {
      int row0 = rowbase + wr * 128 + mr * 16 + kg * 4;
#pragma unroll
      for (int r = 0; r < 4; r++) {
        int row = row0 + r;
        if (row < M) {
          float v = acc[mr][nr][r] + bv;
          if (RELU) v = fmaxf(v, 0.f);
          C[(size_t)row * N + col] = f2bf(v);
        }
      }
    }
  }
}

// flat tile grid: blockIdx.y = global row-tile; tilestart[e] = prefix of ceil(cnt[e]/256).
__device__ __forceinline__ bool tile_lookup(const int* __restrict__ tilestart,
                                            int t, int& e, int& rowtile) {
  int total = tilestart[8];
  if (t >= total) return false;
  e = 0;
#pragma unroll
  for (int i = 1; i < 8; i++) if (t >= tilestart[i]) e = i;
  rowtile = t - tilestart[e];
  return true;
}

__global__ __launch_bounds__(512, 2) void moe_gemm1_kernel(
    const u16* __restrict__ x1b, const u16* __restrict__ W1t,
    const float* __restrict__ B1, u16* __restrict__ he,
    const int* __restrict__ cnt, const int* __restrict__ off,
    const int* __restrict__ tilestart, const int* __restrict__ idxlist) {
  int e, rowtile;
  if (!tile_lookup(tilestart, blockIdx.y, e, rowtile)) return;
  int M = cnt[e];
  gemm256_core<true, true>(x1b, W1t + (size_t)e * DFF * DIMQ, B1 + e * DFF,
                           he + (size_t)off[e] * DFF, M, DFF, DIMQ, idxlist + off[e],
                           rowtile * 256, blockIdx.x * 256);
}

__global__ __launch_bounds__(512, 2) void moe_gemm2_kernel(
    const u16* __restrict__ he, const u16* __restrict__ W2t,
    const float* __restrict__ B2, u16* __restrict__ yslot,
    const int* __restrict__ cnt, const int* __restrict__ off,
    const int* __restrict__ tilestart) {
  int e, rowtile;
  if (!tile_lookup(tilestart, blockIdx.y, e, rowtile)) return;
  int M = cnt[e];
  gemm256_core<false, false>(he + (size_t)off[e] * DFF, W2t + (size_t)e * DIMQ * DFF,
                             B2 + e * DIMQ, yslot + (size_t)off[e] * DIMQ, M, DIMQ, DFF, nullptr,
                             rowtile * 256, blockIdx.x * 256);
}

// ---------------- MFMA flash attention, KVBLK=64 ----------------
__global__ __launch_bounds__(256) void attn_mfma_kernel(
    const u16* __restrict__ qb, const u16* __restrict__ kb,
    const u16* __restrict__ vbT, const int* __restrict__ amask,
    u16* __restrict__ hb) {
  __shared__ u16 Ks[64 * 64];
  __shared__ u16 VTs[64 * 64];
  __shared__ u16 Ps[4][16 * 64];
  __shared__ float mbias[64];

  const int b = blockIdx.y >> 4;
  const int h = blockIdx.y & 15;
  const int qb0 = blockIdx.x * 64;
  const int tid = threadIdx.x;
  const int lane = tid & 63;
  const int wq = tid >> 6;
  const int r16 = lane & 15;
  const int kg = lane >> 4;
  const int qrow0 = qb0 + wq * 16;

  bf16x8 qf[2];
  {
    const u16* qp = qb + ((size_t)(b * TSEQ + qrow0 + r16)) * DIMQ + h * HD + kg * 8;
    qf[0] = *(const bf16x8*)(qp);
    qf[1] = *(const bf16x8*)(qp + 32);
  }
  f32x4 acc[4];
#pragma unroll
  for (int db = 0; db < 4; db++) acc[db] = (f32x4){0.f, 0.f, 0.f, 0.f};
  float m_run[4], l_run[4];
#pragma unroll
  for (int i = 0; i < 4; i++) { m_run[i] = -3.0e38f; l_run[i] = 0.f; }

  const int kr0 = tid >> 3, ks0 = tid & 7;
  const int kr1 = (tid + 256) >> 3, ks1 = tid & 7;
  const u16* kgb = kb + (size_t)(b * TSEQ) * DIMQ + h * HD;
  const u16* vgb = vbT + (size_t)(h * HD) * NTOK + (size_t)b * TSEQ;

  const int nt = (qb0 + 64) >> 6;
  for (int kt = 0; kt < nt; kt++) {
    const int k0g = kt * 64;
    __syncthreads();
    {
      uint4 kv0 = *(const uint4*)(kgb + (size_t)(k0g + kr0) * DIMQ + ks0 * 8);
      *(uint4*)(&Ks[kr0 * 64 + ((ks0 ^ (kr0 & 7)) * 8)]) = kv0;
      uint4 kv1 = *(const uint4*)(kgb + (size_t)(k0g + kr1) * DIMQ + ks1 * 8);
      *(uint4*)(&Ks[kr1 * 64 + ((ks1 ^ (kr1 & 7)) * 8)]) = kv1;
      uint4 vv0 = *(const uint4*)(vgb + (size_t)kr0 * NTOK + k0g + ks0 * 8);
      *(uint4*)(&VTs[kr0 * 64 + ((ks0 ^ (kr0 & 7)) * 8)]) = vv0;
      uint4 vv1 = *(const uint4*)(vgb + (size_t)kr1 * NTOK + k0g + ks1 * 8);
      *(uint4*)(&VTs[kr1 * 64 + ((ks1 ^ (kr1 & 7)) * 8)]) = vv1;
      if (tid < 64) mbias[tid] = amask[b * TSEQ + k0g + tid] ? 0.f : -1e9f;
    }
    __syncthreads();
    if (k0g < qrow0 + 16) {
      f32x4 s[4];
#pragma unroll
      for (int g = 0; g < 4; g++) s[g] = (f32x4){0.f, 0.f, 0.f, 0.f};
#pragma unroll
      for (int g = 0; g < 4; g++) {
        int key = g * 16 + r16;
        bf16x8 ka  = *(const bf16x8*)(&Ks[key * 64 + ((kg ^ (key & 7)) * 8)]);
        bf16x8 kb2 = *(const bf16x8*)(&Ks[key * 64 + (((4 + kg) ^ (key & 7)) * 8)]);
        s[g] = __builtin_amdgcn_mfma_f32_16x16x32_bf16(qf[0], ka, s[g], 0, 0, 0);
        s[g] = __builtin_amdgcn_mfma_f32_16x16x32_bf16(qf[1], kb2, s[g], 0, 0, 0);
      }
      float mb[4] = {mbias[r16], mbias[16 + r16], mbias[32 + r16], mbias[48 + r16]};
      float sv[4][4], tm[4];
#pragma unroll
      for (int i = 0; i < 4; i++) {
        int qg = qrow0 + kg * 4 + i;
        tm[i] = -3.0e38f;
#pragma unroll
        for (int g = 0; g < 4; g++) {
          float a = s[g][i] * 0.125f + mb[g];
          if (k0g + g * 16 + r16 > qg) a = -3.0e38f;
          sv[g][i] = a;
          tm[i] = fmaxf(tm[i], a);
        }
      }
#pragma unroll
      for (int mk = 1; mk < 16; mk <<= 1) {
#pragma unroll
        for (int i = 0; i < 4; i++) tm[i] = fmaxf(tm[i], __shfl_xor(tm[i], mk));
      }
#pragma unroll
      for (int i = 0; i < 4; i++) {
        float nm = fmaxf(m_run[i], tm[i]);
        float sc = __expf(m_run[i] - nm);
        m_run[i] = nm;
        int qrl = kg * 4 + i;
        float lsum = 0.f;
#pragma unroll
        for (int g = 0; g < 4; g++) {
          float p = __expf(sv[g][i] - nm);
          lsum += p;
          int slotL = g * 2 + (r16 >> 3);
          Ps[wq][qrl * 64 + ((slotL ^ (qrl & 7)) * 8) + (r16 & 7)] = f2bf(p);
        }
        l_run[i] = l_run[i] * sc + lsum;
#pragma unroll
        for (int db = 0; db < 4; db++) acc[db][i] *= sc;
      }
      bf16x8 pf0 = *(const bf16x8*)(&Ps[wq][r16 * 64 + ((kg ^ (r16 & 7)) * 8)]);
      bf16x8 pf1 = *(const bf16x8*)(&Ps[wq][r16 * 64 + (((4 + kg) ^ (r16 & 7)) * 8)]);
#pragma unroll
      for (int db = 0; db < 4; db++) {
        int d = db * 16 + r16;
        bf16x8 vf0 = *(const bf16x8*)(&VTs[d * 64 + ((kg ^ (d & 7)) * 8)]);
        bf16x8 vf1 = *(const bf16x8*)(&VTs[d * 64 + (((4 + kg) ^ (d & 7)) * 8)]);
        acc[db] = __builtin_amdgcn_mfma_f32_16x16x32_bf16(pf0, vf0, acc[db], 0, 0, 0);
        acc[db] = __builtin_amdgcn_mfma_f32_16x16x32_bf16(pf1, vf1, acc[db], 0, 0, 0);
      }
    }
  }
#pragma unroll
  for (int mk = 1; mk < 16; mk <<= 1) {
#pragma unroll
    for (int i = 0; i < 4; i++) l_run[i] += __shfl_xor(l_run[i], mk);
  }
#pragma unroll
  for (int i = 0; i < 4; i++) {
    float inv = 1.f / l_run[i];
    int qg = qrow0 + kg * 4 + i;
    u16* op = hb + ((size_t)(b * TSEQ + qg)) * DIMQ + h * HD + r16;
#pragma unroll
    for (int db = 0; db < 4; db++) op[db * 16] = f2bf(acc[db][i] * inv);
  }
}

// ---------------- add + layernorm (x + h) -> x1 f32 and x1b bf16 ----------------
__global__ __launch_bounds__(256) void addln_kernel(
    const float* __restrict__ xin, const u16* __restrict__ hres,
    const float* __restrict__ g, const float* __restrict__ beta,
    float* __restrict__ x1, u16* __restrict__ x1b) {
  __shared__ float red[8];
  int t = blockIdx.x;
  int d = threadIdx.x * 4;
  size_t base = (size_t)t * DIMQ + d;
  float4 xv = *(const float4*)(xin + base);
  uint2 hu = *(const uint2*)(hres + base);
  float v0 = xv.x + bf_lo(hu.x), v1 = xv.y + bf_hi(hu.x);
  float v2 = xv.z + bf_lo(hu.y), v3 = xv.w + bf_hi(hu.y);
  float s1 = v0 + v1 + v2 + v3;
  float s2 = v0 * v0 + v1 * v1 + v2 * v2 + v3 * v3;
#pragma unroll
  for (int off = 32; off; off >>= 1) {
    s1 += __shfl_down(s1, off);
    s2 += __shfl_down(s2, off);
  }
  int w = threadIdx.x >> 6;
  if ((threadIdx.x & 63) == 0) { red[w] = s1; red[4 + w] = s2; }
  __syncthreads();
  float S1 = red[0] + red[1] + red[2] + red[3];
  float S2 = red[4] + red[5] + red[6] + red[7];
  float m = S1 * (1.f / DIMQ);
  float var = S2 * (1.f / DIMQ) - m * m;
  float rs = rsqrtf(var + 1e-5f);
  float4 gv = *(const float4*)(g + d);
  float4 bv = *(const float4*)(beta + d);
  float o0 = (v0 - m) * rs * gv.x + bv.x;
  float o1 = (v1 - m) * rs * gv.y + bv.y;
  float o2 = (v2 - m) * rs * gv.z + bv.z;
  float o3 = (v3 - m) * rs * gv.w + bv.w;
  *(float4*)(x1 + base) = make_float4(o0, o1, o2, o3);
  uint2 pu;
  pu.x = (u32)f2bf(o0) | ((u32)f2bf(o1) << 16);
  pu.y = (u32)f2bf(o2) | ((u32)f2bf(o3) << 16);
  *(uint2*)(x1b + base) = pu;
}

// ---------------- router: logits, softmax, top-2 (NO global atomics) ----------------
__global__ __launch_bounds__(256) void router_kernel(
    const float* __restrict__ x1, const float* __restrict__ rw,
    const float* __restrict__ rb, int* __restrict__ topi,
    float* __restrict__ gkout, float* __restrict__ probs) {
  int t = blockIdx.x * 4 + (threadIdx.x >> 6);
  int l = threadIdx.x & 63;
  float acc[8];
#pragma unroll
  for (int e = 0; e < 8; e++) acc[e] = 0.f;
  const float* xr = x1 + (size_t)t * DIMQ;
  for (int k = l; k < DIMQ; k += 64) {
    float xv = xr[k];
    const float* w = rw + (size_t)k * 8;
#pragma unroll
    for (int e = 0; e < 8; e++) acc[e] += xv * w[e];
  }
#pragma unroll
  for (int e = 0; e < 8; e++) {
#pragma unroll
    for (int off = 32; off; off >>= 1) acc[e] += __shfl_down(acc[e], off);
  }
  if (l == 0) {
    float lg[8], p[8];
    float mx = -3e38f;
#pragma unroll
    for (int e = 0; e < 8; e++) { lg[e] = acc[e] + rb[e]; mx = fmaxf(mx, lg[e]); }
    float sum = 0.f;
#pragma unroll
    for (int e = 0; e < 8; e++) { p[e] = expf(lg[e] - mx); sum += p[e]; }
    float isum = 1.f / sum;
#pragma unroll
    for (int e = 0; e < 8; e++) p[e] *= isum;
    int e0 = 0;
#pragma unroll
    for (int e = 1; e < 8; e++) if (p[e] > p[e0]) e0 = e;
    int e1 = (e0 == 0) ? 1 : 0;
#pragma unroll
    for (int e = 0; e < 8; e++) if (e != e0 && p[e] > p[e1]) e1 = e;
    float s2 = p[e0] + p[e1];
    topi[2 * t] = e0; topi[2 * t + 1] = e1;
    gkout[2 * t] = p[e0] / s2; gkout[2 * t + 1] = p[e1] / s2;
    float* pp = probs + (size_t)t * 8;
#pragma unroll
    for (int e = 0; e < 8; e++) pp[e] = p[e];
  }
}

// ---------------- stats: cnt[e], Psum[e] with block-aggregated atomics ----------------
__global__ __launch_bounds__(256) void stats_kernel(
    const float* __restrict__ probs, const int* __restrict__ topi,
    int* __restrict__ cnt, float* __restrict__ Psum) {
  __shared__ float sps[4][8];
  __shared__ int   slc[4][8];
  float ps[8];
  int lc[8];
#pragma unroll
  for (int e = 0; e < 8; e++) { ps[e] = 0.f; lc[e] = 0; }
  int t = blockIdx.x * 256 + threadIdx.x;
  {
    const float* p = probs + (size_t)t * 8;
#pragma unroll
    for (int e = 0; e < 8; e++) ps[e] += p[e];
    lc[topi[2 * t]]++;
    lc[topi[2 * t + 1]]++;
  }
#pragma unroll
  for (int e = 0; e < 8; e++) {
#pragma unroll
    for (int off = 32; off; off >>= 1) {
      ps[e] += __shfl_down(ps[e], off);
      lc[e] += __shfl_down(lc[e], off);
    }
  }
  int w = threadIdx.x >> 6;
  if ((threadIdx.x & 63) == 0) {
#pragma unroll
    for (int e = 0; e < 8; e++) { sps[w][e] = ps[e]; slc[w][e] = lc[e]; }
  }
  __syncthreads();
  if (threadIdx.x < 8) {
    float fp = sps[0][threadIdx.x] + sps[1][threadIdx.x] + sps[2][threadIdx.x] + sps[3][threadIdx.x];
    int   fc = slc[0][threadIdx.x] + slc[1][threadIdx.x] + slc[2][threadIdx.x] + slc[3][threadIdx.x];
    atomicAdd(&Psum[threadIdx.x], fp);
    atomicAdd(&cnt[threadIdx.x], fc);
  }
}

__global__ void offsets_kernel(const int* __restrict__ cnt, const float* __restrict__ Psum,
                               int* __restrict__ off, int* __restrict__ fill,
                               int* __restrict__ tilestart, float* __restrict__ lb_out) {
  if (threadIdx.x == 0 && blockIdx.x == 0) {
    int o = 0, ts = 0;
    float lb = 0.f;
    for (int e = 0; e < NEXP; e++) {
      off[e] = o;
      fill[e] = o;
      tilestart[e] = ts;
      ts += (cnt[e] + 255) >> 8;
      o += cnt[e];
      lb += ((float)cnt[e] / (float)NTOK) * (Psum[e] / (float)NTOK);
    }
    tilestart[NEXP] = ts;
    lb_out[0] = (float)NEXP * lb;
  }
}

// ---------------- listbuild: block-aggregated slot assignment ----------------
__global__ __launch_bounds__(256) void listbuild_kernel(
    const int* __restrict__ topi, int* fill, int* __restrict__ idxlist,
    int* __restrict__ posmap) {
  __shared__ int bcnt[8];
  __shared__ int base[8];
  __shared__ int bofs[8];
  int t = blockIdx.x * 256 + threadIdx.x;
  if (threadIdx.x < 8) { bcnt[threadIdx.x] = 0; bofs[threadIdx.x] = 0; }
  __syncthreads();
  int e0 = topi[2 * t], e1 = topi[2 * t + 1];
  atomicAdd(&bcnt[e0], 1);
  atomicAdd(&bcnt[e1], 1);
  __syncthreads();
  if (threadIdx.x < 8) base[threadIdx.x] = atomicAdd(&fill[threadIdx.x], bcnt[threadIdx.x]);
  __syncthreads();
  int s0 = base[e0] + atomicAdd(&bofs[e0], 1);
  idxlist[s0] = t;
  posmap[2 * t] = s0;
  int s1 = base[e1] + atomicAdd(&bofs[e1], 1);
  idxlist[s1] = t;
  posmap[2 * t + 1] = s1;
}

// ---------------- final: out = LN(x1 + g0*yslot[p0] + g1*yslot[p1]) ----------------
__global__ __launch_bounds__(256) void finalln_kernel(
    const float* __restrict__ x1, const u16* __restrict__ yslot,
    const int* __restrict__ posmap, const float* __restrict__ gkv,
    const float* __restrict__ g, const float* __restrict__ beta,
    float* __restrict__ out) {
  __shared__ float red[8];
  int t = blockIdx.x;
  int p0 = posmap[2 * t], p1 = posmap[2 * t + 1];
  float g0 = gkv[2 * t], g1 = gkv[2 * t + 1];
  int d = threadIdx.x * 4;
  size_t base = (size_t)t * DIMQ + d;
  float4 xv = *(const float4*)(x1 + base);
  uint2 y0 = *(const uint2*)(yslot + (size_t)p0 * DIMQ + d);
  uint2 y1 = *(const uint2*)(yslot + (size_t)p1 * DIMQ + d);
  float v0 = xv.x + g0 * bf_lo(y0.x) + g1 * bf_lo(y1.x);
  float v1 = xv.y + g0 * bf_hi(y0.x) + g1 * bf_hi(y1.x);
  float v2 = xv.z + g0 * bf_lo(y0.y) + g1 * bf_lo(y1.y);
  float v3 = xv.w + g0 * bf_hi(y0.y) + g1 * bf_hi(y1.y);
  float s1 = v0 + v1 + v2 + v3;
  float s2 = v0 * v0 + v1 * v1 + v2 * v2 + v3 * v3;
#pragma unroll
  for (int off = 32; off; off >>= 1) {
    s1 += __shfl_down(s1, off);
    s2 += __shfl_down(s2, off);
  }
  int w = threadIdx.x >> 6;
  if ((threadIdx.x & 63) == 0) { red[w] = s1; red[4 + w] = s2; }
  __syncthreads();
  float S1 = red[0] + red[1] + red[2] + red[3];
  float S2 = red[4] + red[5] + red[6] + red[7];
  float m = S1 * (1.f / DIMQ);
  float var = S2 * (1.f / DIMQ) - m * m;
  float rs = rsqrtf(var + 1e-5f);
  float4 gv = *(const float4*)(g + d);
  float4 bv = *(const float4*)(beta + d);
  float4 o;
  o.x = (v0 - m) * rs * gv.x + bv.x;
  o.y = (v1 - m) * rs * gv.y + bv.y;
  o.z = (v2 - m) * rs * gv.z + bv.z;
  o.w = (v3 - m) * rs * gv.w + bv.w;
  *(float4*)(out + base) = o;
}

// ---------------- host launch ----------------
extern "C" void kernel_launch(void* const* d_in, const int* in_sizes, int n_in,
                              void* d_out, int out_size, void* d_ws, size_t ws_size,
                              hipStream_t stream) {
  const float* x     = (const float*)d_in[0];
  const int*   amask = (const int*)d_in[1];
  const float* Wq    = (const float*)d_in[2];
  const float* bq    = (const float*)d_in[3];
  const float* Wk    = (const float*)d_in[4];
  const float* bk    = (const float*)d_in[5];
  const float* Wv    = (const float*)d_in[6];
  const float* bv    = (const float*)d_in[7];
  const float* Wo    = (const float*)d_in[8];
  const float* bo    = (const float*)d_in[9];
  const float* g1    = (const float*)d_in[10];
  const float* beta1 = (const float*)d_in[11];
  const float* rw    = (const float*)d_in[12];
  const float* rb    = (const float*)d_in[13];
  const float* W1    = (const float*)d_in[14];
  const float* B1    = (const float*)d_in[15];
  const float* W2    = (const float*)d_in[16];
  const float* B2    = (const float*)d_in[17];
  const float* g2    = (const float*)d_in[18];
  const float* beta2 = (const float*)d_in[19];
  float* out    = (float*)d_out;
  float* lb_out = out + (size_t)NTOK * DIMQ;

  char* ws = (char*)d_ws;
  size_t off_acc = 0;
  auto alloc = [&](size_t bytes) {
    void* p = ws + off_acc;
    off_acc += (bytes + 255) & ~(size_t)255;
    return p;
  };
  u16* xb    = (u16*)alloc((size_t)NTOK * DIMQ * 2);
  u16* qbuf  = (u16*)alloc((size_t)NTOK * DIMQ * 2);
  u16* kbuf  = (u16*)alloc((size_t)NTOK * DIMQ * 2);
  u16* vbufT = (u16*)alloc((size_t)NTOK * DIMQ * 2);  // transposed: [col][row]
  u16* hb    = (u16*)alloc((size_t)NTOK * DIMQ * 2);
  u16* ho    = (u16*)alloc((size_t)NTOK * DIMQ * 2);
  float* x1  = (float*)alloc((size_t)NTOK * DIMQ * 4);
  u16* x1b   = (u16*)alloc((size_t)NTOK * DIMQ * 2);
  u16* Wqt   = (u16*)alloc((size_t)DIMQ * DIMQ * 2);
  u16* Wkt   = (u16*)alloc((size_t)DIMQ * DIMQ * 2);
  u16* Wvt   = (u16*)alloc((size_t)DIMQ * DIMQ * 2);
  u16* Wot   = (u16*)alloc((size_t)DIMQ * DIMQ * 2);
  u16* W1t   = (u16*)alloc((size_t)NEXP * DFF * DIMQ * 2);
  u16* W2t   = (u16*)alloc((size_t)NEXP * DIMQ * DFF * 2);
  u16* he    = (u16*)alloc((size_t)2 * NTOK * DFF * 2);
  u16* yslot = (u16*)alloc((size_t)2 * NTOK * DIMQ * 2);
  char* stats = (char*)alloc(4096);
  int*   cnt   = (int*)stats;
  float* Psum  = (float*)(stats + 32);
  int*   offp  = (int*)(stats + 64);
  int*   fill  = (int*)(stats + 96);
  int*   tilestart = (int*)(stats + 128);   // 9 ints
  int* topi    = (int*)alloc((size_t)NTOK * 2 * 4);
  float* gkbuf = (float*)alloc((size_t)NTOK * 2 * 4);
  int* posmap  = (int*)alloc((size_t)NTOK * 2 * 4);
  int* idxlist = (int*)alloc((size_t)NTOK * 2 * 4);
  float* probs = (float*)alloc((size_t)NTOK * 8 * 4);

  hipMemsetAsync(stats, 0, 192, stream);

  // converts / transposes
  cvt_f32_bf16<<<NTOK * DIMQ / 1024, 256, 0, stream>>>(x, xb, NTOK * DIMQ);
  transpose_f32_bf16<<<dim3(DIMQ / 32, DIMQ / 32, 1), 256, 0, stream>>>(Wq, Wqt, DIMQ, DIMQ);
  transpose_f32_bf16<<<dim3(DIMQ / 32, DIMQ / 32, 1), 256, 0, stream>>>(Wk, Wkt, DIMQ, DIMQ);
  transpose_f32_bf16<<<dim3(DIMQ / 32, DIMQ / 32, 1), 256, 0, stream>>>(Wv, Wvt, DIMQ, DIMQ);
  transpose_f32_bf16<<<dim3(DIMQ / 32, DIMQ / 32, 1), 256, 0, stream>>>(Wo, Wot, DIMQ, DIMQ);
  transpose_f32_bf16<<<dim3(DFF / 32, DIMQ / 32, NEXP), 256, 0, stream>>>(W1, W1t, DIMQ, DFF);
  transpose_f32_bf16<<<dim3(DIMQ / 32, DFF / 32, NEXP), 256, 0, stream>>>(W2, W2t, DFF, DIMQ);

  // attention path
  dim3 gproj(DIMQ / 128, NTOK / 128);
  gemm_bt_kernel<<<gproj, 256, 0, stream>>>(xb, Wqt, bq, qbuf, NTOK, DIMQ, DIMQ);
  gemm_bt_kernel<<<gproj, 256, 0, stream>>>(xb, Wkt, bk, kbuf, NTOK, DIMQ, DIMQ);
  gemm_bt_tc_kernel<<<gproj, 256, 0, stream>>>(xb, Wvt, bv, vbufT, NTOK, DIMQ, DIMQ);
  attn_mfma_kernel<<<dim3(TSEQ / 64, BATCH * NHEADS), 256, 0, stream>>>(qbuf, kbuf, vbufT, amask, hb);
  gemm_bt_kernel<<<gproj, 256, 0, stream>>>(hb, Wot, bo, ho, NTOK, DIMQ, DIMQ);
  addln_kernel<<<NTOK, 256, 0, stream>>>(x, ho, g1, beta1, x1, x1b);

  // MoE path
  router_kernel<<<NTOK / 4, 256, 0, stream>>>(x1, rw, rb, topi, gkbuf, probs);
  stats_kernel<<<NTOK / 256, 256, 0, stream>>>(probs, topi, cnt, Psum);
  offsets_kernel<<<1, 64, 0, stream>>>(cnt, Psum, offp, fill, tilestart, lb_out);
  listbuild_kernel<<<NTOK / 256, 256, 0, stream>>>(topi, fill, idxlist, posmap);
  moe_gemm1_kernel<<<dim3(DFF / 256, MAXTILES, 1), 512, 0, stream>>>(x1b, W1t, B1, he, cnt, offp, tilestart, idxlist);
  moe_gemm2_kernel<<<dim3(DIMQ / 256, MAXTILES, 1), 512, 0, stream>>>(he, W2t, B2, yslot, cnt, offp, tilestart);
  finalln_kernel<<<NTOK, 256, 0, stream>>>(x1, yslot, posmap, gkbuf, g2, beta2, out);
}